// Round 1
// baseline (369.651 us; speedup 1.0000x reference)
//
#include <hip/hip_runtime.h>

#define BUCKETS_LOG2 22
#define BUCKET_MASK ((1u << BUCKETS_LOG2) - 1u)
#define BLOCK 256

__global__ __launch_bounds__(BLOCK) void hash_trilerp_kernel(
    const float* __restrict__ pts,          // (N,3)
    const float* __restrict__ vf,           // (BUCKETS, 8)
    const unsigned int* __restrict__ primes,// (3,)
    float* __restrict__ out,                // (N,8)
    int n)
{
    __shared__ float sp[3 * BLOCK];

    const int tid = threadIdx.x;
    const int i = blockIdx.x * BLOCK + tid;

    // Coalesced staging of pts (AoS stride-3) through LDS
    {
        const int base = blockIdx.x * BLOCK * 3;
        const int total = n * 3;
        #pragma unroll
        for (int k = 0; k < 3; ++k) {
            int idx = base + k * BLOCK + tid;
            if (idx < total) sp[k * BLOCK + tid] = pts[idx];
        }
    }
    __syncthreads();

    if (i >= n) return;

    const unsigned int p0 = primes[0];
    const unsigned int p1 = primes[1];
    const unsigned int p2 = primes[2];

    const float px = sp[3 * tid + 0];
    const float py = sp[3 * tid + 1];
    const float pz = sp[3 * tid + 2];

    // q = pts / RES, RES = 1/1024 (exact power of two -> multiply is exact)
    const float qx = px * 1024.0f;
    const float qy = py * 1024.0f;
    const float qz = pz * 1024.0f;

    const float bxf = floorf(qx);
    const float byf = floorf(qy);
    const float bzf = floorf(qz);
    const float fx = qx - bxf, fy = qy - byf, fz = qz - bzf;

    const unsigned int bx = (unsigned int)(int)bxf;
    const unsigned int by = (unsigned int)(int)byf;
    const unsigned int bz = (unsigned int)(int)bzf;

    // hash partials (uint32 wraparound semantics, matches reference)
    unsigned int hx[2], hy[2], hz[2];
    hx[0] = bx * p0; hx[1] = hx[0] + p0;
    hy[0] = by * p1; hy[1] = hy[0] + p1;
    hz[0] = bz * p2; hz[1] = hz[0] + p2;

    float wx[2] = { 1.0f - fx, fx };
    float wy[2] = { 1.0f - fy, fy };
    float wz[2] = { 1.0f - fz, fz };

    const float4* __restrict__ v4 = (const float4*)vf;

    float4 a0 = make_float4(0.f, 0.f, 0.f, 0.f);
    float4 a1 = make_float4(0.f, 0.f, 0.f, 0.f);

    #pragma unroll
    for (int cz = 0; cz < 2; ++cz) {
        #pragma unroll
        for (int cy = 0; cy < 2; ++cy) {
            #pragma unroll
            for (int cx = 0; cx < 2; ++cx) {
                const unsigned int vid = (hx[cx] + hy[cy] + hz[cz]) & BUCKET_MASK;
                const float w = wx[cx] * wy[cy] * wz[cz];
                const size_t off = (size_t)vid * 2u;
                const float4 f0 = v4[off];
                const float4 f1 = v4[off + 1];
                a0.x += w * f0.x; a0.y += w * f0.y;
                a0.z += w * f0.z; a0.w += w * f0.w;
                a1.x += w * f1.x; a1.y += w * f1.y;
                a1.z += w * f1.z; a1.w += w * f1.w;
            }
        }
    }

    float4* __restrict__ o4 = (float4*)out;
    o4[(size_t)i * 2u]      = a0;
    o4[(size_t)i * 2u + 1u] = a1;
}

extern "C" void kernel_launch(void* const* d_in, const int* in_sizes, int n_in,
                              void* d_out, int out_size, void* d_ws, size_t ws_size,
                              hipStream_t stream) {
    const float* pts            = (const float*)d_in[0];
    const float* vf             = (const float*)d_in[1];
    const unsigned int* primes  = (const unsigned int*)d_in[2];
    float* out                  = (float*)d_out;

    const int n = in_sizes[0] / 3;   // N_PTS
    const int grid = (n + BLOCK - 1) / BLOCK;
    hash_trilerp_kernel<<<grid, BLOCK, 0, stream>>>(pts, vf, primes, out, n);
}